// Round 2
// baseline (3292.107 us; speedup 1.0000x reference)
//
#include <hip/hip_runtime.h>
#include <hip/hip_bf16.h>
#include <math.h>

#define HW 1024
#define CDIM 384
#define FUSED_CH 768
#define DW_CH 744
#define NB 32
#define EPS 1e-5f

typedef __hip_bfloat16 bf16;

// ---------------- LN1 stats: per-batch mean/rstd over (C,H,W) ----------------
__global__ void k_stats1(const float* __restrict__ x, float* __restrict__ stats) {
  int b = blockIdx.x;
  const float* xb = x + (size_t)b * CDIM * HW;
  float s = 0.f, s2 = 0.f;
  for (int i = threadIdx.x; i < CDIM * HW; i += 256) {
    float v = xb[i];
    s += v; s2 += v * v;
  }
  __shared__ float ls[256], ls2[256];
  ls[threadIdx.x] = s; ls2[threadIdx.x] = s2;
  __syncthreads();
  for (int off = 128; off > 0; off >>= 1) {
    if (threadIdx.x < off) {
      ls[threadIdx.x] += ls[threadIdx.x + off];
      ls2[threadIdx.x] += ls2[threadIdx.x + off];
    }
    __syncthreads();
  }
  if (threadIdx.x == 0) {
    const float inv_n = 1.f / (CDIM * HW);
    float m = ls[0] * inv_n;
    float v = ls2[0] * inv_n - m * m;
    stats[b] = m;
    stats[32 + b] = rsqrtf(v + EPS);
  }
}

// ---------------- proj_in with LN1 fused into the input load, bf16 out ------
__global__ void k_proj_in(const float* __restrict__ W, const float* __restrict__ x,
                          const float* __restrict__ lnw, const float* __restrict__ lnb,
                          const float* __restrict__ stats, const float* __restrict__ bias,
                          bf16* __restrict__ Out) {
  __shared__ float Ws[8][65];
  __shared__ float Is[8][65];
  const int b = blockIdx.z;
  const int o0 = blockIdx.y * 64;
  const int p0 = blockIdx.x * 64;
  const float m = stats[b], rs = stats[32 + b];
  const float* xb = x + (size_t)b * CDIM * HW;
  const int t = threadIdx.y * 16 + threadIdx.x;
  float acc[4][4] = {};
  for (int k0 = 0; k0 < CDIM; k0 += 8) {
    for (int idx = t; idx < 512; idx += 256) {
      int kk = idx & 7, oo = idx >> 3;
      Ws[kk][oo] = W[(size_t)(o0 + oo) * CDIM + k0 + kk];
    }
    for (int idx = t; idx < 512; idx += 256) {
      int pp = idx & 63, kk = idx >> 6;
      int chw = (k0 + kk) * HW + p0 + pp;
      Is[kk][pp] = (xb[chw] - m) * rs * lnw[chw] + lnb[chw];
    }
    __syncthreads();
#pragma unroll
    for (int kk = 0; kk < 8; kk++) {
      float a[4], bv[4];
#pragma unroll
      for (int i = 0; i < 4; i++) a[i] = Ws[kk][threadIdx.y * 4 + i];
#pragma unroll
      for (int j = 0; j < 4; j++) bv[j] = Is[kk][threadIdx.x * 4 + j];
#pragma unroll
      for (int i = 0; i < 4; i++)
#pragma unroll
        for (int j = 0; j < 4; j++) acc[i][j] += a[i] * bv[j];
    }
    __syncthreads();
  }
#pragma unroll
  for (int i = 0; i < 4; i++) {
    int o = o0 + threadIdx.y * 4 + i;
    float bo = bias[o];
#pragma unroll
    for (int j = 0; j < 4; j++) {
      int p = p0 + threadIdx.x * 4 + j;
      Out[((size_t)b * FUSED_CH + o) * HW + p] = __float2bfloat16(acc[i][j] + bo);
    }
  }
}

// ---------------- generic 1x1-conv GEMM (fp32 in/out, bf16 gate) ----------------
// MODE 1: * gate[b][gate_off + o][p]   (pw stages)
// MODE 2: res[b][o][p] + gvec[o]*val   (proj_out)
// MODE 3: gelu(val)                    (fc1)
// MODE 4: res[b][o][p] + gvec[o]*val   (fc2)
__device__ __forceinline__ float gelu_exact(float v) {
  return 0.5f * v * (1.f + erff(v * 0.70710678118654752f));
}

template <int MODE>
__global__ void k_gemm(const float* __restrict__ W, const float* __restrict__ In,
                       const float* __restrict__ bias, float* __restrict__ Out,
                       int O, int C, const bf16* __restrict__ gate, int gate_off,
                       const float* __restrict__ res, const float* __restrict__ gvec) {
  __shared__ float Ws[8][65];
  __shared__ float Is[8][65];
  const int b = blockIdx.z;
  const int o0 = blockIdx.y * 64;
  const int p0 = blockIdx.x * 64;
  const float* Inb = In + (size_t)b * C * HW;
  const int t = threadIdx.y * 16 + threadIdx.x;
  float acc[4][4] = {};
  for (int k0 = 0; k0 < C; k0 += 8) {
    for (int idx = t; idx < 512; idx += 256) {
      int kk = idx & 7, oo = idx >> 3;
      int o = o0 + oo;
      Ws[kk][oo] = (o < O) ? W[(size_t)o * C + k0 + kk] : 0.f;
    }
    for (int idx = t; idx < 512; idx += 256) {
      int pp = idx & 63, kk = idx >> 6;
      Is[kk][pp] = Inb[(size_t)(k0 + kk) * HW + p0 + pp];
    }
    __syncthreads();
#pragma unroll
    for (int kk = 0; kk < 8; kk++) {
      float a[4], bv[4];
#pragma unroll
      for (int i = 0; i < 4; i++) a[i] = Ws[kk][threadIdx.y * 4 + i];
#pragma unroll
      for (int j = 0; j < 4; j++) bv[j] = Is[kk][threadIdx.x * 4 + j];
#pragma unroll
      for (int i = 0; i < 4; i++)
#pragma unroll
        for (int j = 0; j < 4; j++) acc[i][j] += a[i] * bv[j];
    }
    __syncthreads();
  }
#pragma unroll
  for (int i = 0; i < 4; i++) {
    int o = o0 + threadIdx.y * 4 + i;
    if (o >= O) continue;
    float bo = bias[o];
#pragma unroll
    for (int j = 0; j < 4; j++) {
      int p = p0 + threadIdx.x * 4 + j;
      float val = acc[i][j] + bo;
      size_t oidx = ((size_t)b * O + o) * HW + p;
      if (MODE == 1) {
        Out[oidx] = val * __bfloat162float(gate[((size_t)b * DW_CH + gate_off + o) * HW + p]);
      } else if (MODE == 2 || MODE == 4) {
        Out[oidx] = res[oidx] + gvec[o] * val;
      } else if (MODE == 3) {
        Out[oidx] = gelu_exact(val);
      }
    }
  }
}

// ---------------- depthwise 7x7 conv (bf16 in, bf16 out) ----------------
__global__ void k_dwconv(const bf16* __restrict__ fused, const float* __restrict__ w,
                         const float* __restrict__ bias, bf16* __restrict__ out) {
  const int c = blockIdx.x;  // 0..743
  const int b = blockIdx.y;
  const bf16* in = fused + ((size_t)b * FUSED_CH + (24 + c)) * HW;
  __shared__ float tile[38][38];
  __shared__ float wk[49];
  const int t = threadIdx.x;
  if (t < 49) wk[t] = w[c * 49 + t];
  for (int idx = t; idx < 38 * 38; idx += 256) {
    int yy = idx / 38 - 3, xx = idx % 38 - 3;
    tile[idx / 38][idx % 38] =
        (yy >= 0 && yy < 32 && xx >= 0 && xx < 32) ? __bfloat162float(in[yy * 32 + xx]) : 0.f;
  }
  __syncthreads();
  const float bv = bias[c];
  bf16* ob = out + ((size_t)b * DW_CH + c) * HW;
  for (int idx = t; idx < 1024; idx += 256) {
    int yy = idx >> 5, xx = idx & 31;
    float acc = 0.f;
#pragma unroll
    for (int ky = 0; ky < 7; ky++)
#pragma unroll
      for (int kx = 0; kx < 7; kx++) acc += tile[yy + ky][xx + kx] * wk[ky * 7 + kx];
    ob[idx] = __float2bfloat16((acc + bv) * (1.f / 3.f));
  }
}

// ---------------- y0 = pwa * dw[:24] ----------------
__global__ void k_y0(const bf16* __restrict__ fused, const bf16* __restrict__ dw,
                     float* __restrict__ y0) {
  int i = blockIdx.x * 256 + threadIdx.x;  // 32*24*1024 total
  int b = i / (24 * HW);
  int r = i % (24 * HW);
  y0[i] = __bfloat162float(fused[(size_t)b * FUSED_CH * HW + r]) *
          __bfloat162float(dw[(size_t)b * DW_CH * HW + r]);
}

// ---------------- LN2 (per-position over channels, NCHW strided) ----------------
__global__ void k_ln2(const float* __restrict__ xm, const float* __restrict__ w,
                      const float* __restrict__ bb, float* __restrict__ out) {
  int g = blockIdx.x * 256 + threadIdx.x;  // 0..32767
  int b = g >> 10, p = g & 1023;
  const float* xb = xm + (size_t)b * CDIM * HW + p;
  float s = 0.f, s2 = 0.f;
  for (int c = 0; c < CDIM; c++) {
    float v = xb[(size_t)c * HW];
    s += v; s2 += v * v;
  }
  const float inv_n = 1.f / CDIM;
  float m = s * inv_n;
  float va = s2 * inv_n - m * m;
  float rs = rsqrtf(va + EPS);
  float* ob = out + (size_t)b * CDIM * HW + p;
  for (int c = 0; c < CDIM; c++) {
    float v = xb[(size_t)c * HW];
    ob[(size_t)c * HW] = (v - m) * rs * w[c] + bb[c];
  }
}

extern "C" void kernel_launch(void* const* d_in, const int* in_sizes, int n_in,
                              void* d_out, int out_size, void* d_ws, size_t ws_size,
                              hipStream_t stream) {
  const float* x          = (const float*)d_in[0];
  const float* ln1_w      = (const float*)d_in[1];
  const float* ln1_b      = (const float*)d_in[2];
  const float* proj_in_w  = (const float*)d_in[3];
  const float* proj_in_b  = (const float*)d_in[4];
  const float* dw_w       = (const float*)d_in[5];
  const float* dw_b       = (const float*)d_in[6];
  const float* pw0_w      = (const float*)d_in[7];
  const float* pw0_b      = (const float*)d_in[8];
  const float* pw1_w      = (const float*)d_in[9];
  const float* pw1_b      = (const float*)d_in[10];
  const float* pw2_w      = (const float*)d_in[11];
  const float* pw2_b      = (const float*)d_in[12];
  const float* pw3_w      = (const float*)d_in[13];
  const float* pw3_b      = (const float*)d_in[14];
  const float* proj_out_w = (const float*)d_in[15];
  const float* proj_out_b = (const float*)d_in[16];
  const float* ln2_w      = (const float*)d_in[17];
  const float* ln2_b      = (const float*)d_in[18];
  const float* fc1_w      = (const float*)d_in[19];
  const float* fc1_b      = (const float*)d_in[20];
  const float* fc2_w      = (const float*)d_in[21];
  const float* fc2_b      = (const float*)d_in[22];
  const float* gamma1     = (const float*)d_in[23];
  const float* gamma2     = (const float*)d_in[24];
  float* out = (float*)d_out;

  const size_t MiB = 1ull << 20;
  char* ws = (char*)d_ws;
  // Live-range-overlapped layout; peak 144 MiB.
  bf16*  fused  = (bf16*)(ws + 0);            // [0,48) bf16, dead after k_y0
  bf16*  dw     = (bf16*)(ws + 48 * MiB);     // [48,94.5) bf16, dead after pw3
  float* stats  = (float*)(ws + 48 * MiB);    // 64 floats, dead after proj_in (pre-dw)
  float* y0     = (float*)(ws + 95 * MiB);    // [95,98), dead after pw0
  float* y1     = (float*)(ws + 0);           // [0,6)   (fused dead)
  float* y2     = (float*)(ws + 6 * MiB);     // [6,18)
  float* y3     = (float*)(ws + 18 * MiB);    // [18,42)
  float* y4     = (float*)(ws + 95 * MiB);    // [95,143) (y0 dead)
  float* xmid   = (float*)(ws + 0);           // [0,48)  (y1..y3,fused dead)
  float* ln2h   = (float*)(ws + 48 * MiB);    // [48,96) (dw,y0 dead; y4 dead post proj_out)
  float* fc1tmp = (float*)(ws + 96 * MiB);    // [96,144) (y4 dead)

  dim3 tb(16, 16);

  k_stats1<<<NB, 256, 0, stream>>>(x, stats);
  // proj_in with fused LN1: 768 x 384
  k_proj_in<<<dim3(16, 12, NB), tb, 0, stream>>>(proj_in_w, x, ln1_w, ln1_b, stats,
                                                 proj_in_b, fused);
  // depthwise 7x7 on fused[24:768]
  k_dwconv<<<dim3(DW_CH, NB), 256, 0, stream>>>(fused, dw_w, dw_b, dw);
  // y0 = pwa * dw[:24]
  k_y0<<<(NB * 24 * HW) / 256, 256, 0, stream>>>(fused, dw, y0);
  // pw chain (gates are dw channel slices)
  k_gemm<1><<<dim3(16, 1, NB), tb, 0, stream>>>(pw0_w, y0, pw0_b, y1, 48, 24, dw, 24,
                                                nullptr, nullptr);
  k_gemm<1><<<dim3(16, 2, NB), tb, 0, stream>>>(pw1_w, y1, pw1_b, y2, 96, 48, dw, 72,
                                                nullptr, nullptr);
  k_gemm<1><<<dim3(16, 3, NB), tb, 0, stream>>>(pw2_w, y2, pw2_b, y3, 192, 96, dw, 168,
                                                nullptr, nullptr);
  k_gemm<1><<<dim3(16, 6, NB), tb, 0, stream>>>(pw3_w, y3, pw3_b, y4, 384, 192, dw, 360,
                                                nullptr, nullptr);
  // proj_out + gamma1 residual -> xmid
  k_gemm<2><<<dim3(16, 6, NB), tb, 0, stream>>>(proj_out_w, y4, proj_out_b, xmid, 384,
                                                384, nullptr, 0, x, gamma1);
  // LN2
  k_ln2<<<(NB * HW) / 256, 256, 0, stream>>>(xmid, ln2_w, ln2_b, ln2h);
  // MLP in 4 chunks of 8 batches (keeps GELU intermediate at 48 MiB)
  for (int b0 = 0; b0 < NB; b0 += 8) {
    k_gemm<3><<<dim3(16, 24, 8), tb, 0, stream>>>(fc1_w, ln2h + (size_t)b0 * CDIM * HW,
                                                  fc1_b, fc1tmp, 1536, 384, nullptr, 0,
                                                  nullptr, nullptr);
    k_gemm<4><<<dim3(16, 6, 8), tb, 0, stream>>>(fc2_w, fc1tmp, fc2_b,
                                                 out + (size_t)b0 * CDIM * HW, 384, 1536,
                                                 nullptr, 0, xmid + (size_t)b0 * CDIM * HW,
                                                 gamma2);
  }
}

// Round 3
// 475.386 us; speedup vs baseline: 6.9251x; 6.9251x over previous
//
#include <hip/hip_runtime.h>
#include <math.h>

#define HW 1024
#define CDIM 384
#define NB 32
#define MTOT (NB * HW)   // 32768 rows in NHWC
#define EPS 1e-5f

typedef short s8v __attribute__((ext_vector_type(8)));
typedef float f4v __attribute__((ext_vector_type(4)));
typedef unsigned short ushort_t;

union U8 { s8v v; unsigned short u[8]; };

__device__ __forceinline__ float bf2f(unsigned short u) {
  union { float f; unsigned int i; } x; x.i = ((unsigned int)u) << 16; return x.f;
}
__device__ __forceinline__ unsigned short f2bf(float f) {
  union { float f; unsigned int i; } x; x.f = f;
  unsigned int r = (x.i + 0x7FFFu + ((x.i >> 16) & 1u)) >> 16;
  return (unsigned short)r;
}
__device__ __forceinline__ float gelu_exact(float v) {
  return 0.5f * v * (1.f + erff(v * 0.70710678118654752f));
}

// ---------------- LN1 stats, two-stage ----------------
__global__ __launch_bounds__(256) void k_statsA(const float* __restrict__ x,
                                                float* __restrict__ part) {
  int blk = blockIdx.x;  // b*32 + slice, 1024 blocks, 12288 elems each
  const float4* xb = (const float4*)(x + (size_t)blk * 12288);
  float s = 0.f, s2 = 0.f;
  for (int i = threadIdx.x; i < 3072; i += 256) {
    float4 v = xb[i];
    s += v.x + v.y + v.z + v.w;
    s2 += v.x * v.x + v.y * v.y + v.z * v.z + v.w * v.w;
  }
  __shared__ float ls[256], ls2[256];
  ls[threadIdx.x] = s; ls2[threadIdx.x] = s2;
  __syncthreads();
  for (int off = 128; off > 0; off >>= 1) {
    if (threadIdx.x < off) {
      ls[threadIdx.x] += ls[threadIdx.x + off];
      ls2[threadIdx.x] += ls2[threadIdx.x + off];
    }
    __syncthreads();
  }
  if (threadIdx.x == 0) { part[blk * 2] = ls[0]; part[blk * 2 + 1] = ls2[0]; }
}

__global__ void k_statsB(const float* __restrict__ part, float* __restrict__ stats) {
  int b = threadIdx.x;
  if (b >= 32) return;
  float s = 0.f, s2 = 0.f;
  for (int i = 0; i < 32; i++) {
    s += part[(b * 32 + i) * 2];
    s2 += part[(b * 32 + i) * 2 + 1];
  }
  const float inv_n = 1.f / (CDIM * HW);
  float m = s * inv_n;
  stats[b] = m;
  stats[32 + b] = rsqrtf(s2 * inv_n - m * m + EPS);
}

// ---------------- NCHW -> NHWC transpose + LN1 apply ----------------
// outputs: xn (bf16 NHWC of raw x), hn (bf16 NHWC of LN1(x))
__global__ __launch_bounds__(256) void k_trln1(const float* __restrict__ x,
                                               const float* __restrict__ lnw,
                                               const float* __restrict__ lnb,
                                               const float* __restrict__ stats,
                                               unsigned short* __restrict__ xn,
                                               unsigned short* __restrict__ hn) {
  int pt = blockIdx.x, ct = blockIdx.y, b = blockIdx.z;
  __shared__ float xs[32][33], hs[32][33];
  float m = stats[b], rs = stats[32 + b];
  int t = threadIdx.x;
  int ci0 = t >> 5, pi = t & 31;
#pragma unroll
  for (int it = 0; it < 4; it++) {
    int ci = ci0 + it * 8;
    int c = ct * 32 + ci;
    size_t src = ((size_t)b * CDIM + c) * HW + pt * 32 + pi;
    size_t wsrc = (size_t)c * HW + pt * 32 + pi;
    float xv = x[src];
    xs[ci][pi] = xv;
    hs[ci][pi] = (xv - m) * rs * lnw[wsrc] + lnb[wsrc];
  }
  __syncthreads();
  int co = t & 31, pr0 = t >> 5;
#pragma unroll
  for (int it = 0; it < 4; it++) {
    int pr = pr0 + it * 8;
    int p = pt * 32 + pr;
    int c = ct * 32 + co;
    size_t dst = ((size_t)b * HW + p) * CDIM + c;
    xn[dst] = f2bf(xs[co][pr]);
    hn[dst] = f2bf(hs[co][pr]);
  }
}

// ---------------- MFMA GEMM: Out[p][o] = epi(sum_k A[p][k]*W[o][k] + bias[o]) ----
// A: bf16 row-major (M x K). W: f32 row-major (O x K), converted to bf16 in staging.
// MODE 0: bf16 store               (proj_in -> fused, stride O)
// MODE 1: * gate, bf16 store      (pw stages; gate bf16 stride 744 at gate_off)
// MODE 2: f32 store: bf2f(xres_bf[p*384+o]) + gvec[o]*val   (proj_out -> xmid)
// MODE 3: gelu -> bf16            (fc1 -> h1)
// MODE 4: d_out NCHW f32: xmid_f[gp*384+o] + gvec[o]*val    (fc2)
template <int MODE>
__global__ __launch_bounds__(256)
void k_mm(const unsigned short* __restrict__ A, const float* __restrict__ Wf,
          const float* __restrict__ bias, void* __restrict__ Out,
          const unsigned short* __restrict__ gate, int gate_off,
          const unsigned short* __restrict__ xres_bf, const float* __restrict__ xmid_f,
          const float* __restrict__ gvec, int m_base, int K, int O) {
  __shared__ unsigned short As[64][40];
  __shared__ unsigned short Bs[64][40];
  const int t = threadIdx.x;
  const int m0 = blockIdx.x * 64;
  const int o0 = blockIdx.y * 64;
  const int lane = t & 63, wave = t >> 6;
  const int wm = (wave >> 1) * 32, wn = (wave & 1) * 32;
  const int lr = lane & 15, lk = (lane >> 4) * 8;
  const int srow = t >> 2, soff = (t & 3) * 8;

  f4v acc[2][2];
  acc[0][0] = {}; acc[0][1] = {}; acc[1][0] = {}; acc[1][1] = {};

  for (int k0 = 0; k0 < K; k0 += 32) {
    // stage A (bf16 direct)
    {
      U8 av;
      if (k0 + soff + 8 <= K) {
        av.v = *(const s8v*)(A + (size_t)(m0 + srow) * K + k0 + soff);
      } else {
        for (int i = 0; i < 8; i++) av.u[i] = 0;
      }
      *(s8v*)&As[srow][soff] = av.v;
    }
    // stage B = W row (f32 -> bf16)
    {
      U8 bv;
      int o = o0 + srow;
      if (o < O && k0 + soff + 8 <= K) {
        const float* wr = Wf + (size_t)o * K + k0 + soff;
        f4v w0 = *(const f4v*)wr;
        f4v w1 = *(const f4v*)(wr + 4);
#pragma unroll
        for (int i = 0; i < 4; i++) { bv.u[i] = f2bf(w0[i]); bv.u[4 + i] = f2bf(w1[i]); }
      } else {
        for (int i = 0; i < 8; i++) bv.u[i] = 0;
      }
      *(s8v*)&Bs[srow][soff] = bv.v;
    }
    __syncthreads();
    s8v a0 = *(const s8v*)&As[wm + lr][lk];
    s8v a1 = *(const s8v*)&As[wm + 16 + lr][lk];
    s8v b0 = *(const s8v*)&Bs[wn + lr][lk];
    s8v b1 = *(const s8v*)&Bs[wn + 16 + lr][lk];
    acc[0][0] = __builtin_amdgcn_mfma_f32_16x16x32_bf16(a0, b0, acc[0][0], 0, 0, 0);
    acc[0][1] = __builtin_amdgcn_mfma_f32_16x16x32_bf16(a0, b1, acc[0][1], 0, 0, 0);
    acc[1][0] = __builtin_amdgcn_mfma_f32_16x16x32_bf16(a1, b0, acc[1][0], 0, 0, 0);
    acc[1][1] = __builtin_amdgcn_mfma_f32_16x16x32_bf16(a1, b1, acc[1][1], 0, 0, 0);
    __syncthreads();
  }

#pragma unroll
  for (int fi = 0; fi < 2; fi++)
#pragma unroll
    for (int fj = 0; fj < 2; fj++) {
      int o = o0 + wn + fj * 16 + lr;
      if (o >= O) continue;
      int p0 = m0 + wm + fi * 16 + (lane >> 4) * 4;
      float bo = bias[o];
      if (MODE == 4) {
        int gp = m_base + p0;
        float4 st;
        float* stp = &st.x;
#pragma unroll
        for (int r = 0; r < 4; r++)
          stp[r] = xmid_f[(size_t)(gp + r) * CDIM + o] + gvec[o] * (acc[fi][fj][r] + bo);
        int bb = gp >> 10, hw = gp & 1023;
        *(float4*)((float*)Out + ((size_t)bb * CDIM + o) * HW + hw) = st;
      } else {
#pragma unroll
        for (int r = 0; r < 4; r++) {
          float val = acc[fi][fj][r] + bo;
          int p = p0 + r;
          if (MODE == 0) {
            ((unsigned short*)Out)[(size_t)p * O + o] = f2bf(val);
          } else if (MODE == 1) {
            float g = bf2f(gate[(size_t)p * 744 + gate_off + o]);
            ((unsigned short*)Out)[(size_t)p * O + o] = f2bf(val * g);
          } else if (MODE == 2) {
            ((float*)Out)[(size_t)p * CDIM + o] =
                bf2f(xres_bf[(size_t)p * CDIM + o]) + gvec[o] * val;
          } else if (MODE == 3) {
            ((unsigned short*)Out)[(size_t)p * O + o] = f2bf(gelu_exact(val));
          }
        }
      }
    }
}

// ---------------- depthwise 7x7, NHWC, channel-64 slabs ----------------
__global__ __launch_bounds__(256) void k_dwconv(const unsigned short* __restrict__ fused,
                                                const float* __restrict__ w,
                                                const float* __restrict__ bias,
                                                unsigned short* __restrict__ dwo) {
  int ys = blockIdx.x;   // 8 strips of 4 rows
  int cb = blockIdx.y;   // 12 channel blocks of 64
  int b = blockIdx.z;
  __shared__ unsigned short tile[10][32][64];
  __shared__ float wk[64][49];
  int c0 = cb * 64;
  int t = threadIdx.x;
  for (int i = t; i < 64 * 49; i += 256) {
    int c = i / 49, k = i % 49;
    wk[c][k] = (c0 + c < 744) ? w[(size_t)(c0 + c) * 49 + k] : 0.f;
  }
  int lx = t >> 3, lco = (t & 7) * 8;
  for (int yy = 0; yy < 10; yy++) {
    int y = ys * 4 - 3 + yy;
    U8 v;
    int fch = 24 + c0 + lco;
    if (y >= 0 && y < 32 && fch + 8 <= 768) {
      v.v = *(const s8v*)(fused + ((size_t)b * HW + y * 32 + lx) * 768 + fch);
    } else if (y >= 0 && y < 32) {
      for (int i = 0; i < 8; i++)
        v.u[i] = (fch + i < 768) ? fused[((size_t)b * HW + y * 32 + lx) * 768 + fch + i] : 0;
    } else {
      for (int i = 0; i < 8; i++) v.u[i] = 0;
    }
    *(s8v*)&tile[yy][lx][lco] = v.v;
  }
  __syncthreads();
  int c = t & 63, dy = t >> 6;
  bool valid = (c0 + c) < 744;
  float bv = valid ? bias[c0 + c] : 0.f;
  float acc[32];
#pragma unroll
  for (int x = 0; x < 32; x++) acc[x] = 0.f;
#pragma unroll
  for (int ky = 0; ky < 7; ky++) {
    int yy = dy + ky;
    float r[38];
    r[0] = r[1] = r[2] = 0.f; r[35] = r[36] = r[37] = 0.f;
#pragma unroll
    for (int x = 0; x < 32; x++) r[x + 3] = bf2f(tile[yy][x][c]);
#pragma unroll
    for (int kx = 0; kx < 7; kx++) {
      float wv = wk[c][ky * 7 + kx];
#pragma unroll
      for (int x = 0; x < 32; x++) acc[x] += r[x + kx] * wv;
    }
  }
  if (valid) {
    int yout = ys * 4 + dy;
#pragma unroll
    for (int x = 0; x < 32; x++) {
      dwo[((size_t)b * HW + yout * 32 + x) * 744 + c0 + c] =
          f2bf((acc[x] + bv) * (1.f / 3.f));
    }
  }
}

// ---------------- y0 = pwa * dw[:,:24] ----------------
__global__ __launch_bounds__(256) void k_y0(const unsigned short* __restrict__ fused,
                                            const unsigned short* __restrict__ dwo,
                                            unsigned short* __restrict__ y0) {
  int i = blockIdx.x * 256 + threadIdx.x;  // MTOT*24
  int p = i / 24, c = i % 24;
  y0[i] = f2bf(bf2f(fused[(size_t)p * 768 + c]) * bf2f(dwo[(size_t)p * 744 + c]));
}

// ---------------- LN2: per-row over 384 contiguous channels ----------------
__global__ __launch_bounds__(256) void k_ln2(const float* __restrict__ xmid,
                                             const float* __restrict__ w,
                                             const float* __restrict__ bb,
                                             unsigned short* __restrict__ out) {
  int row = blockIdx.x * 4 + (threadIdx.x >> 6);
  int lane = threadIdx.x & 63;
  const float* xr = xmid + (size_t)row * CDIM;
  float v[6];
  float s = 0.f, s2 = 0.f;
#pragma unroll
  for (int k = 0; k < 6; k++) {
    v[k] = xr[k * 64 + lane];
    s += v[k]; s2 += v[k] * v[k];
  }
#pragma unroll
  for (int off = 32; off > 0; off >>= 1) {
    s += __shfl_xor(s, off);
    s2 += __shfl_xor(s2, off);
  }
  const float inv_n = 1.f / CDIM;
  float m = s * inv_n;
  float rs = rsqrtf(s2 * inv_n - m * m + EPS);
#pragma unroll
  for (int k = 0; k < 6; k++) {
    int c = k * 64 + lane;
    out[(size_t)row * CDIM + c] = f2bf((v[k] - m) * rs * w[c] + bb[c]);
  }
}

extern "C" void kernel_launch(void* const* d_in, const int* in_sizes, int n_in,
                              void* d_out, int out_size, void* d_ws, size_t ws_size,
                              hipStream_t stream) {
  const float* x          = (const float*)d_in[0];
  const float* ln1_w      = (const float*)d_in[1];
  const float* ln1_b      = (const float*)d_in[2];
  const float* proj_in_w  = (const float*)d_in[3];
  const float* proj_in_b  = (const float*)d_in[4];
  const float* dw_w       = (const float*)d_in[5];
  const float* dw_b       = (const float*)d_in[6];
  const float* pw0_w      = (const float*)d_in[7];
  const float* pw0_b      = (const float*)d_in[8];
  const float* pw1_w      = (const float*)d_in[9];
  const float* pw1_b      = (const float*)d_in[10];
  const float* pw2_w      = (const float*)d_in[11];
  const float* pw2_b      = (const float*)d_in[12];
  const float* pw3_w      = (const float*)d_in[13];
  const float* pw3_b      = (const float*)d_in[14];
  const float* proj_out_w = (const float*)d_in[15];
  const float* proj_out_b = (const float*)d_in[16];
  const float* ln2_w      = (const float*)d_in[17];
  const float* ln2_b      = (const float*)d_in[18];
  const float* fc1_w      = (const float*)d_in[19];
  const float* fc1_b      = (const float*)d_in[20];
  const float* fc2_w      = (const float*)d_in[21];
  const float* fc2_b      = (const float*)d_in[22];
  const float* gamma1     = (const float*)d_in[23];
  const float* gamma2     = (const float*)d_in[24];
  float* out = (float*)d_out;

  const size_t MiB = 1ull << 20;
  char* ws = (char*)d_ws;
  // Live-range-overlapped NHWC layout, peak 144 MiB:
  unsigned short* xn   = (unsigned short*)(ws + 0);          // [0,24) bf16 x NHWC
  unsigned short* hn   = (unsigned short*)(ws + 24 * MiB);   // [24,48) bf16 LN1(x)
  unsigned short* fus  = (unsigned short*)(ws + 48 * MiB);   // [48,96) bf16 32768x768
  unsigned short* dw   = (unsigned short*)(ws + 96 * MiB);   // [96,142.5) bf16 32768x744
  float* stats = (float*)(ws + 142 * MiB + 600 * 1024);      // dead before dwconv writes
  float* part  = stats + 64;
  unsigned short* y0 = (unsigned short*)(ws + 24 * MiB);          // [24,25.5)
  unsigned short* y1 = (unsigned short*)(ws + 25 * MiB + 512 * 1024);
  unsigned short* y2 = (unsigned short*)(ws + 28 * MiB + 512 * 1024);
  unsigned short* y3 = (unsigned short*)(ws + 34 * MiB + 512 * 1024);  // 12 MiB
  unsigned short* y4 = (unsigned short*)(ws + 48 * MiB);     // [48,72) after fused dead
  float* xmid = (float*)(ws + 96 * MiB);                     // [96,144) after dw dead
  unsigned short* ln2h = (unsigned short*)(ws + 0);          // [0,24) after xn dead
  unsigned short* h1 = (unsigned short*)(ws + 24 * MiB);     // [24,72) chunk 48 MiB

  // LN1 stats (two-stage)
  k_statsA<<<1024, 256, 0, stream>>>(x, part);
  k_statsB<<<1, 64, 0, stream>>>(part, stats);
  // transpose + LN1 apply
  k_trln1<<<dim3(32, 12, NB), 256, 0, stream>>>(x, ln1_w, ln1_b, stats, xn, hn);
  // proj_in: (32768x384)x(768x384)^T -> fused bf16
  k_mm<0><<<dim3(512, 12), 256, 0, stream>>>(hn, proj_in_w, proj_in_b, fus, nullptr, 0,
                                             nullptr, nullptr, nullptr, 0, 384, 768);
  // depthwise 7x7
  k_dwconv<<<dim3(8, 12, NB), 256, 0, stream>>>(fus, dw_w, dw_b, dw);
  // y0
  k_y0<<<(MTOT * 24) / 256, 256, 0, stream>>>(fus, dw, y0);
  // pw chain with gates
  k_mm<1><<<dim3(512, 1), 256, 0, stream>>>(y0, pw0_w, pw0_b, y1, dw, 24, nullptr,
                                            nullptr, nullptr, 0, 24, 48);
  k_mm<1><<<dim3(512, 2), 256, 0, stream>>>(y1, pw1_w, pw1_b, y2, dw, 72, nullptr,
                                            nullptr, nullptr, 0, 48, 96);
  k_mm<1><<<dim3(512, 3), 256, 0, stream>>>(y2, pw2_w, pw2_b, y3, dw, 168, nullptr,
                                            nullptr, nullptr, 0, 96, 192);
  k_mm<1><<<dim3(512, 6), 256, 0, stream>>>(y3, pw3_w, pw3_b, y4, dw, 360, nullptr,
                                            nullptr, nullptr, 0, 192, 384);
  // proj_out + gamma1 residual -> xmid (f32 NHWC)
  k_mm<2><<<dim3(512, 6), 256, 0, stream>>>(y4, proj_out_w, proj_out_b, xmid, nullptr, 0,
                                            xn, nullptr, gamma1, 0, 384, 384);
  // LN2
  k_ln2<<<MTOT / 4, 256, 0, stream>>>(xmid, ln2_w, ln2_b, ln2h);
  // MLP in 2 chunks of 16 batches
  for (int ch = 0; ch < 2; ch++) {
    int m_base = ch * 16384;
    k_mm<3><<<dim3(256, 24), 256, 0, stream>>>(ln2h + (size_t)m_base * CDIM, fc1_w, fc1_b,
                                               h1, nullptr, 0, nullptr, nullptr, nullptr,
                                               0, 384, 1536);
    k_mm<4><<<dim3(256, 6), 256, 0, stream>>>(h1, fc2_w, fc2_b, out, nullptr, 0, nullptr,
                                              xmid, gamma2, m_base, 1536, 384);
  }
}

// Round 4
// 436.758 us; speedup vs baseline: 7.5376x; 1.0884x over previous
//
#include <hip/hip_runtime.h>
#include <math.h>

#define HW 1024
#define CDIM 384
#define NB 32
#define MTOT (NB * HW)
#define EPS 1e-5f

typedef unsigned short u16;
typedef short s8v __attribute__((ext_vector_type(8)));
typedef float f4v __attribute__((ext_vector_type(4)));

union U8 { s8v v; u16 u[8]; };

__device__ __forceinline__ float bf2f(u16 u) {
  union { float f; unsigned int i; } x; x.i = ((unsigned int)u) << 16; return x.f;
}
__device__ __forceinline__ u16 f2bf(float f) {
  union { float f; unsigned int i; } x; x.f = f;
  unsigned int r = (x.i + 0x7FFFu + ((x.i >> 16) & 1u)) >> 16;
  return (u16)r;
}
__device__ __forceinline__ float gelu_exact(float v) {
  return 0.5f * v * (1.f + erff(v * 0.70710678118654752f));
}

// async global->LDS, 16B per lane; LDS dest = wave-uniform base + lane*16
__device__ __forceinline__ void gload16(const u16* g, u16* l) {
  __builtin_amdgcn_global_load_lds(
      (const __attribute__((address_space(1))) unsigned int*)(unsigned long long)(const void*)g,
      (__attribute__((address_space(3))) unsigned int*)(unsigned int)(unsigned long long)(void*)l,
      16, 0, 0);
}

// ---------------- LN1 stats, two-stage ----------------
__global__ __launch_bounds__(256) void k_statsA(const float* __restrict__ x,
                                                float* __restrict__ part) {
  int blk = blockIdx.x;
  const float4* xb = (const float4*)(x + (size_t)blk * 12288);
  float s = 0.f, s2 = 0.f;
  for (int i = threadIdx.x; i < 3072; i += 256) {
    float4 v = xb[i];
    s += v.x + v.y + v.z + v.w;
    s2 += v.x * v.x + v.y * v.y + v.z * v.z + v.w * v.w;
  }
  __shared__ float ls[256], ls2[256];
  ls[threadIdx.x] = s; ls2[threadIdx.x] = s2;
  __syncthreads();
  for (int off = 128; off > 0; off >>= 1) {
    if (threadIdx.x < off) {
      ls[threadIdx.x] += ls[threadIdx.x + off];
      ls2[threadIdx.x] += ls2[threadIdx.x + off];
    }
    __syncthreads();
  }
  if (threadIdx.x == 0) { part[blk * 2] = ls[0]; part[blk * 2 + 1] = ls2[0]; }
}

__global__ void k_statsB(const float* __restrict__ part, float* __restrict__ stats) {
  int b = threadIdx.x;
  if (b >= 32) return;
  float s = 0.f, s2 = 0.f;
  for (int i = 0; i < 32; i++) {
    s += part[(b * 32 + i) * 2];
    s2 += part[(b * 32 + i) * 2 + 1];
  }
  const float inv_n = 1.f / (CDIM * HW);
  float m = s * inv_n;
  stats[b] = m;
  stats[32 + b] = rsqrtf(s2 * inv_n - m * m + EPS);
}

// ---------------- weight f32->bf16 conversion ----------------
__global__ __launch_bounds__(256) void k_cvtwE(const float* __restrict__ piw,
                                               const float* __restrict__ pow_,
                                               const float* __restrict__ p0w,
                                               const float* __restrict__ p1w,
                                               const float* __restrict__ p2w,
                                               const float* __restrict__ p3w,
                                               u16* __restrict__ dst) {
  int i = blockIdx.x * 256 + threadIdx.x;  // 542208 total
  if (i < 294912) dst[i] = f2bf(piw[i]);
  else if (i < 442368) dst[i] = f2bf(pow_[i - 294912]);
  else if (i < 443904) { int j = i - 442368, o = j >> 5, k = j & 31;
    dst[i] = (k < 24) ? f2bf(p0w[o * 24 + k]) : (u16)0; }
  else if (i < 450048) { int j = i - 443904, o = j >> 6, k = j & 63;
    dst[i] = (k < 48) ? f2bf(p1w[o * 48 + k]) : (u16)0; }
  else if (i < 468480) dst[i] = f2bf(p2w[i - 450048]);
  else dst[i] = f2bf(p3w[i - 468480]);
}

__global__ __launch_bounds__(256) void k_cvtwL(const float* __restrict__ fc1,
                                               const float* __restrict__ fc2,
                                               u16* __restrict__ dst) {
  int i = blockIdx.x * 256 + threadIdx.x;  // 1179648 total
  if (i < 589824) dst[i] = f2bf(fc1[i]);
  else dst[i] = f2bf(fc2[i - 589824]);
}

// ---------------- NCHW -> NHWC transpose + LN1 apply ----------------
__global__ __launch_bounds__(256) void k_trln1(const float* __restrict__ x,
                                               const float* __restrict__ lnw,
                                               const float* __restrict__ lnb,
                                               const float* __restrict__ stats,
                                               u16* __restrict__ xn,
                                               u16* __restrict__ hn) {
  int pt = blockIdx.x, ct = blockIdx.y, b = blockIdx.z;
  __shared__ float xs[32][33], hs[32][33];
  float m = stats[b], rs = stats[32 + b];
  int t = threadIdx.x;
  int ci0 = t >> 5, pi = t & 31;
#pragma unroll
  for (int it = 0; it < 4; it++) {
    int ci = ci0 + it * 8;
    int c = ct * 32 + ci;
    size_t src = ((size_t)b * CDIM + c) * HW + pt * 32 + pi;
    size_t wsrc = (size_t)c * HW + pt * 32 + pi;
    float xv = x[src];
    xs[ci][pi] = xv;
    hs[ci][pi] = (xv - m) * rs * lnw[wsrc] + lnb[wsrc];
  }
  __syncthreads();
  int co = t & 31, pr0 = t >> 5;
#pragma unroll
  for (int it = 0; it < 4; it++) {
    int pr = pr0 + it * 8;
    int p = pt * 32 + pr;
    int c = ct * 32 + co;
    size_t dst = ((size_t)b * HW + p) * CDIM + c;
    xn[dst] = f2bf(xs[co][pr]);
    hn[dst] = f2bf(hs[co][pr]);
  }
}

// ---------------- m97-style 128x128 MFMA GEMM ----------------
// Out[p][o] = epi(sum_k A[p][k]*Wb[o][k] + bias[o]); A,Wb bf16 row-major stride K.
// MODE 0: bf16 store stride OS                  (proj_in)
// MODE 1: *gate (dw stride 744 @gate_off), bf16 store stride OS, zero-pad o in [O,OS)
// MODE 2: bf16 store: bf2f(resbf)+gvec[o]*val   (proj_out -> xmid bf16)
// MODE 3: gelu -> bf16 stride OS                (fc1)
// MODE 4: f32 NCHW d_out: bf2f(resbf)+gvec[o]*val, rows offset by m_base (fc2)
template <int MODE>
__global__ __launch_bounds__(256)
void k_mfma(const u16* __restrict__ A, const u16* __restrict__ Wb,
            const float* __restrict__ bias, void* __restrict__ Out,
            const u16* __restrict__ gate, int gate_off,
            const u16* __restrict__ resbf, const float* __restrict__ gvec,
            int m_base, int K, int O, int OS) {
  __shared__ u16 As[4096];
  __shared__ u16 Bs[4096];
  const int t = threadIdx.x;
  const int m0 = blockIdx.x * 128, o0 = blockIdx.y * 128;
  const int w = t >> 6, l = t & 63;
  const int wm = (w >> 1) * 64, wn = (w & 1) * 64;
  const int lr = l & 15, lk = (l >> 4) * 8;

  const u16* gA = A + (size_t)(m0 + w * 32 + (l >> 2)) * K + (l & 3) * 8;
  const u16* gB = Wb + (size_t)(o0 + w * 32 + (l >> 2)) * K + (l & 3) * 8;
  u16* ldsA0 = As + w * 1024;
  u16* ldsB0 = Bs + w * 1024;

  f4v acc[4][4];
#pragma unroll
  for (int i = 0; i < 4; i++)
#pragma unroll
    for (int j = 0; j < 4; j++) acc[i][j] = {};

  for (int k0 = 0; k0 < K; k0 += 32) {
    gload16(gA + k0, ldsA0);
    gload16(gA + 16 * K + k0, ldsA0 + 512);
    gload16(gB + k0, ldsB0);
    gload16(gB + 16 * K + k0, ldsB0 + 512);
    __syncthreads();
    s8v a[4], b[4];
#pragma unroll
    for (int mi = 0; mi < 4; mi++)
      a[mi] = *(const s8v*)&As[(wm + mi * 16 + lr) * 32 + lk];
#pragma unroll
    for (int fj = 0; fj < 4; fj++)
      b[fj] = *(const s8v*)&Bs[(wn + fj * 16 + lr) * 32 + lk];
#pragma unroll
    for (int mi = 0; mi < 4; mi++)
#pragma unroll
      for (int fj = 0; fj < 4; fj++)
        acc[mi][fj] = __builtin_amdgcn_mfma_f32_16x16x32_bf16(a[mi], b[fj], acc[mi][fj], 0, 0, 0);
    __syncthreads();
  }

  const int orow = (l >> 4) * 4;
#pragma unroll
  for (int mi = 0; mi < 4; mi++) {
    int p = m0 + wm + mi * 16 + orow;
#pragma unroll
    for (int fj = 0; fj < 4; fj++) {
      int o = o0 + wn + fj * 16 + lr;
      if (MODE == 1 && o >= OS) continue;
      float bo = (MODE == 1 && o >= O) ? 0.f : bias[o];
      float gv = (MODE == 2 || MODE == 4) ? gvec[o] : 0.f;
      if (MODE == 4) {
        int gp = m_base + p;
        float4 st;
        float* stp = &st.x;
#pragma unroll
        for (int r = 0; r < 4; r++)
          stp[r] = bf2f(resbf[(size_t)(gp + r) * CDIM + o]) + gv * (acc[mi][fj][r] + bo);
        int bb = gp >> 10, hw = gp & 1023;
        *(float4*)((float*)Out + ((size_t)bb * CDIM + o) * HW + hw) = st;
      } else {
#pragma unroll
        for (int r = 0; r < 4; r++) {
          float val = acc[mi][fj][r] + bo;
          size_t rowi = (size_t)(p + r);
          if (MODE == 0) {
            ((u16*)Out)[rowi * OS + o] = f2bf(val);
          } else if (MODE == 1) {
            float g = (o < O) ? bf2f(gate[rowi * 744 + gate_off + o]) : 0.f;
            ((u16*)Out)[rowi * OS + o] = (o < O) ? f2bf(val * g) : (u16)0;
          } else if (MODE == 2) {
            size_t idx = rowi * CDIM + o;
            ((u16*)Out)[idx] = f2bf(bf2f(resbf[idx]) + gv * val);
          } else if (MODE == 3) {
            ((u16*)Out)[rowi * OS + o] = f2bf(gelu_exact(val));
          }
        }
      }
    }
  }
}

// ---------------- depthwise 7x7, NHWC, channel-64 slabs ----------------
__global__ __launch_bounds__(256) void k_dwconv(const u16* __restrict__ fused,
                                                const float* __restrict__ w,
                                                const float* __restrict__ bias,
                                                u16* __restrict__ dwo) {
  int ys = blockIdx.x;
  int cb = blockIdx.y;
  int b = blockIdx.z;
  __shared__ u16 tile[10][32][64];
  __shared__ float wk[64][49];
  int c0 = cb * 64;
  int t = threadIdx.x;
  for (int i = t; i < 64 * 49; i += 256) {
    int c = i / 49, k = i % 49;
    wk[c][k] = (c0 + c < 744) ? w[(size_t)(c0 + c) * 49 + k] : 0.f;
  }
  int lx = t >> 3, lco = (t & 7) * 8;
  for (int yy = 0; yy < 10; yy++) {
    int y = ys * 4 - 3 + yy;
    U8 v;
    int fch = 24 + c0 + lco;
    if (y >= 0 && y < 32 && fch + 8 <= 768) {
      v.v = *(const s8v*)(fused + ((size_t)b * HW + y * 32 + lx) * 768 + fch);
    } else if (y >= 0 && y < 32) {
      for (int i = 0; i < 8; i++)
        v.u[i] = (fch + i < 768) ? fused[((size_t)b * HW + y * 32 + lx) * 768 + fch + i] : 0;
    } else {
      for (int i = 0; i < 8; i++) v.u[i] = 0;
    }
    *(s8v*)&tile[yy][lx][lco] = v.v;
  }
  __syncthreads();
  int c = t & 63, dy = t >> 6;
  bool valid = (c0 + c) < 744;
  float bv = valid ? bias[c0 + c] : 0.f;
  float acc[32];
#pragma unroll
  for (int x = 0; x < 32; x++) acc[x] = 0.f;
#pragma unroll
  for (int ky = 0; ky < 7; ky++) {
    int yy = dy + ky;
    float r[38];
    r[0] = r[1] = r[2] = 0.f; r[35] = r[36] = r[37] = 0.f;
#pragma unroll
    for (int x = 0; x < 32; x++) r[x + 3] = bf2f(tile[yy][x][c]);
#pragma unroll
    for (int kx = 0; kx < 7; kx++) {
      float wv = wk[c][ky * 7 + kx];
#pragma unroll
      for (int x = 0; x < 32; x++) acc[x] += r[x + kx] * wv;
    }
  }
  if (valid) {
    int yout = ys * 4 + dy;
#pragma unroll
    for (int x = 0; x < 32; x++) {
      dwo[((size_t)b * HW + yout * 32 + x) * 744 + c0 + c] =
          f2bf((acc[x] + bv) * (1.f / 3.f));
    }
  }
}

// ---------------- y0 = pwa * dw[:,:24], padded stride 32 ----------------
__global__ __launch_bounds__(256) void k_y0(const u16* __restrict__ fused,
                                            const u16* __restrict__ dwo,
                                            u16* __restrict__ y0) {
  int i = blockIdx.x * 256 + threadIdx.x;  // MTOT*32
  int p = i >> 5, c = i & 31;
  y0[i] = (c < 24) ? f2bf(bf2f(fused[(size_t)p * 768 + c]) * bf2f(dwo[(size_t)p * 744 + c]))
                   : (u16)0;
}

// ---------------- LN2 (row over 384 contiguous channels, bf16 in/out) ----------------
__global__ __launch_bounds__(256) void k_ln2(const u16* __restrict__ xm,
                                             const float* __restrict__ w,
                                             const float* __restrict__ bb,
                                             u16* __restrict__ outp) {
  int row = blockIdx.x * 4 + (threadIdx.x >> 6);
  int l = threadIdx.x & 63;
  float v[8];
  float s = 0.f, s2 = 0.f;
  if (l < 48) {
    U8 u;
    u.v = *(const s8v*)(xm + (size_t)row * CDIM + l * 8);
#pragma unroll
    for (int i = 0; i < 8; i++) {
      v[i] = bf2f(u.u[i]);
      s += v[i]; s2 += v[i] * v[i];
    }
  }
#pragma unroll
  for (int off = 32; off > 0; off >>= 1) {
    s += __shfl_xor(s, off);
    s2 += __shfl_xor(s2, off);
  }
  const float inv_n = 1.f / CDIM;
  float m = s * inv_n;
  float rs = rsqrtf(s2 * inv_n - m * m + EPS);
  if (l < 48) {
    U8 res;
#pragma unroll
    for (int i = 0; i < 8; i++) {
      int c = l * 8 + i;
      res.u[i] = f2bf((v[i] - m) * rs * w[c] + bb[c]);
    }
    *(s8v*)(outp + (size_t)row * CDIM + l * 8) = res.v;
  }
}

extern "C" void kernel_launch(void* const* d_in, const int* in_sizes, int n_in,
                              void* d_out, int out_size, void* d_ws, size_t ws_size,
                              hipStream_t stream) {
  const float* x          = (const float*)d_in[0];
  const float* ln1_w      = (const float*)d_in[1];
  const float* ln1_b      = (const float*)d_in[2];
  const float* proj_in_w  = (const float*)d_in[3];
  const float* proj_in_b  = (const float*)d_in[4];
  const float* dw_w       = (const float*)d_in[5];
  const float* dw_b       = (const float*)d_in[6];
  const float* pw0_w      = (const float*)d_in[7];
  const float* pw0_b      = (const float*)d_in[8];
  const float* pw1_w      = (const float*)d_in[9];
  const float* pw1_b      = (const float*)d_in[10];
  const float* pw2_w      = (const float*)d_in[11];
  const float* pw2_b      = (const float*)d_in[12];
  const float* pw3_w      = (const float*)d_in[13];
  const float* pw3_b      = (const float*)d_in[14];
  const float* proj_out_w = (const float*)d_in[15];
  const float* proj_out_b = (const float*)d_in[16];
  const float* ln2_w      = (const float*)d_in[17];
  const float* ln2_b      = (const float*)d_in[18];
  const float* fc1_w      = (const float*)d_in[19];
  const float* fc1_b      = (const float*)d_in[20];
  const float* fc2_w      = (const float*)d_in[21];
  const float* fc2_b      = (const float*)d_in[22];
  const float* gamma1     = (const float*)d_in[23];
  const float* gamma2     = (const float*)d_in[24];
  float* out = (float*)d_out;

  const size_t MiB = 1ull << 20;
  char* ws = (char*)d_ws;
  // Layout (peak exactly 144 MiB, proven safe):
  u16* xn   = (u16*)(ws + 0);            // [0,24) x bf16 NHWC; dead after proj_out
  u16* hn   = (u16*)(ws + 24 * MiB);     // [24,48); dead after proj_in
  u16* fus  = (u16*)(ws + 48 * MiB);     // [48,96); dead after y0
  u16* dw   = (u16*)(ws + 96 * MiB);     // [96,142.5); dead after pw3
  u16* wE   = (u16*)(ws + 142 * MiB + 512 * 1024);  // early bf16 weights, 1.04 MiB
  float* stats = (float*)(ws + 143 * MiB + 768 * 1024);  // 64 + 2048 floats
  float* part  = stats + 64;
  u16* y0 = (u16*)(ws + 24 * MiB);       // [24,26) stride 32
  u16* y1 = (u16*)(ws + 26 * MiB);       // [26,30) stride 64 (48 + pad)
  u16* y2 = (u16*)(ws + 30 * MiB);       // [30,36) stride 96
  u16* y3 = (u16*)(ws + 36 * MiB);       // [36,48) stride 192
  u16* y4 = (u16*)(ws + 48 * MiB);       // [48,72) stride 384 (fus dead)
  u16* xmid = (u16*)(ws + 72 * MiB);     // [72,96) bf16 NHWC
  u16* ln2h = (u16*)(ws + 0);            // [0,24) (xn dead after proj_out)
  u16* fc1b = (u16*)(ws + 24 * MiB);     // [24,26.25) late weights (y* dead)
  u16* fc2b = fc1b + 589824;
  u16* h1 = (u16*)(ws + 96 * MiB);       // [96,144) 16-batch chunk (dw, wE, stats dead)

  u16* piw_b = wE;
  u16* pow_b = wE + 294912;
  u16* pw0b  = wE + 442368;
  u16* pw1b  = wE + 443904;
  u16* pw2b  = wE + 450048;
  u16* pw3b  = wE + 468480;

  k_statsA<<<1024, 256, 0, stream>>>(x, part);
  k_statsB<<<1, 64, 0, stream>>>(part, stats);
  k_cvtwE<<<2118, 256, 0, stream>>>(proj_in_w, proj_out_w, pw0_w, pw1_w, pw2_w, pw3_w, wE);
  k_trln1<<<dim3(32, 12, NB), 256, 0, stream>>>(x, ln1_w, ln1_b, stats, xn, hn);
  // proj_in: M=32768, K=384, O=768
  k_mfma<0><<<dim3(256, 6), 256, 0, stream>>>(hn, piw_b, proj_in_b, fus, nullptr, 0,
                                              nullptr, nullptr, 0, 384, 768, 768);
  k_dwconv<<<dim3(8, 12, NB), 256, 0, stream>>>(fus, dw_w, dw_b, dw);
  k_y0<<<(MTOT * 32) / 256, 256, 0, stream>>>(fus, dw, y0);
  // pw chain
  k_mfma<1><<<dim3(256, 1), 256, 0, stream>>>(y0, pw0b, pw0_b, y1, dw, 24, nullptr,
                                              nullptr, 0, 32, 48, 64);
  k_mfma<1><<<dim3(256, 1), 256, 0, stream>>>(y1, pw1b, pw1_b, y2, dw, 72, nullptr,
                                              nullptr, 0, 64, 96, 96);
  k_mfma<1><<<dim3(256, 2), 256, 0, stream>>>(y2, pw2b, pw2_b, y3, dw, 168, nullptr,
                                              nullptr, 0, 96, 192, 192);
  k_mfma<1><<<dim3(256, 3), 256, 0, stream>>>(y3, pw3b, pw3_b, y4, dw, 360, nullptr,
                                              nullptr, 0, 192, 384, 384);
  // proj_out + gamma1 residual -> xmid (bf16)
  k_mfma<2><<<dim3(256, 3), 256, 0, stream>>>(y4, pow_b, proj_out_b, xmid, nullptr, 0,
                                              xn, gamma1, 0, 384, 384, 384);
  k_ln2<<<MTOT / 4, 256, 0, stream>>>(xmid, ln2_w, ln2_b, ln2h);
  k_cvtwL<<<4608, 256, 0, stream>>>(fc1_w, fc2_w, fc1b);
  // MLP in 2 chunks of 16 batches
  for (int ch = 0; ch < 2; ch++) {
    int m_base = ch * 16384;
    k_mfma<3><<<dim3(128, 12), 256, 0, stream>>>(ln2h + (size_t)m_base * CDIM, fc1b,
                                                 fc1_b, h1, nullptr, 0, nullptr, nullptr,
                                                 0, 384, 1536, 1536);
    k_mfma<4><<<dim3(128, 3), 256, 0, stream>>>(h1, fc2b, fc2_b, out, nullptr, 0, xmid,
                                                gamma2, m_base, 1536, 384, 384);
  }
}